// Round 1
// baseline (8990.531 us; speedup 1.0000x reference)
//
#include <hip/hip_runtime.h>
#include <cstdint>
#include <cstddef>

#define B_MOL 512
#define A_PER 64
#define ED_PER 256
#define N_ATOMS (B_MOL * A_PER)   // 32768
#define N_DIR (B_MOL * ED_PER)    // 131072
#define N_UND (B_MOL * 128)       // 65536
#define HID 256
#define OUT_STRIDE 12289

__device__ __forceinline__ int e_src(int e) {
  return (e < 64) ? e : (e < 128) ? (e - 64)
       : (e < 192) ? ((e - 127) & 63) : ((e - 190) & 63);
}

// ---------------------------------------------------------------------------
// fgemm128: fp32 LDS GEMM, 128x128 tile, BK=16, 256 threads, 64 out/thread
// (four 4x4 quadrants). A staged TRANSPOSED into As[k][m] so the inner loop
// reads both operands as float4 (ds_read_b128), conflict-free patterns:
//   a: 4 unique 16B lines broadcast; b: 64 consecutive words = 2-way (free).
// AMODE: 0 dense fp32 A [M,lda];
//        2 W_o concat: k<256 -> A(asumf)[row*256+k], k>=256 -> A2(f_atoms)
//          [row*98+k-256]; B rows remapped (98+k / k-256);
//        3 VcVv: k<256 -> A(afat), k>=256 -> A2(prev_hid); B transposed:
//          k<256 -> B(W_vc)[n][k], else B2(W_vv)[n][k-256];
//        4 bond-pair gather of fp32 atom_feats (K=512).
// outmode: 0 fp32 dense float4 stores (requires N%128==0 — true at all call
//          sites); 2 atom-head strided scalar stores.
// ---------------------------------------------------------------------------
template <int AMODE>
__launch_bounds__(256)
__global__ void fgemm128(const float* __restrict__ A, const float* __restrict__ A2,
                         const float* __restrict__ B, const float* __restrict__ B2,
                         const float* __restrict__ addend,
                         const float* __restrict__ bias,
                         float* __restrict__ outf,
                         int M, int N, int K, int lda, int ldb, int ldco, int outcol,
                         int relu, int outmode) {
  __shared__ float As[16][132];   // [k][m], row stride 132 floats = 33*16B aligned
  __shared__ float Bs[16][132];   // [k][n]
  const int tid = threadIdx.x;
  const int tx = tid & 15, ty = tid >> 4;
  const int tileM = blockIdx.x * 128, tileN = blockIdx.y * 128;
  float acc[2][2][4][4] = {};     // [rowquad p][colquad q][i][j]

  const int nkb = (K + 15) >> 4;
  for (int kb = 0; kb < nkb; ++kb) {
    __syncthreads();
    // stage A: 128 rows x 16 k, transposed -> As[k][m]; 8 floats/thread
    {
      const int m = tid >> 1;
      const int k0 = (tid & 1) * 8;
      const int row = tileM + m;
#pragma unroll
      for (int z = 0; z < 8; ++z) {
        int k = kb * 16 + k0 + z;
        float v = 0.f;
        if (k < K) {
          if (AMODE == 0) v = A[(size_t)row * lda + k];
          else if (AMODE == 2) v = (k < 256) ? A[(size_t)row * 256 + k]
                                             : A2[(size_t)row * 98 + (k - 256)];
          else if (AMODE == 3) v = (k < 256) ? A[(size_t)row * 256 + k]
                                             : A2[(size_t)row * 256 + (k - 256)];
          else {  // AMODE 4: bond gather
            int mol = row >> 7, u = row & 127;
            int a0i = (u < 64) ? u : (u - 64);
            int a1i = (u < 64) ? ((u + 1) & 63) : ((u - 62) & 63);
            int atom = (k < 256) ? a0i : a1i;
            v = A[(size_t)(mol * 64 + atom) * 256 + (k & 255)];
          }
        }
        As[k0 + z][m] = v;
      }
    }
    // stage B: 16 k x 128 n; 8 floats/thread, coalesced on n
#pragma unroll
    for (int it = 0; it < 8; ++it) {
      int e = it * 256 + tid;
      int kk = e >> 7, n = e & 127;
      int k = kb * 16 + kk, nn = tileN + n;
      float v = 0.f;
      if (k < K && nn < N) {
        if (AMODE == 2) v = (k < 256) ? B[(size_t)(98 + k) * ldb + nn]
                                      : B[(size_t)(k - 256) * ldb + nn];
        else if (AMODE == 3) v = (k < 256) ? B[(size_t)nn * 256 + k]
                                           : B2[(size_t)nn * 256 + (k - 256)];
        else v = B[(size_t)k * ldb + nn];
      }
      Bs[kk][n] = v;
    }
    __syncthreads();
#pragma unroll
    for (int kk = 0; kk < 16; ++kk) {
      const float4 a0 = *(const float4*)&As[kk][ty * 4];
      const float4 a1 = *(const float4*)&As[kk][ty * 4 + 64];
      const float4 b0 = *(const float4*)&Bs[kk][tx * 4];
      const float4 b1 = *(const float4*)&Bs[kk][tx * 4 + 64];
      const float a[2][4] = {{a0.x, a0.y, a0.z, a0.w}, {a1.x, a1.y, a1.z, a1.w}};
      const float b[2][4] = {{b0.x, b0.y, b0.z, b0.w}, {b1.x, b1.y, b1.z, b1.w}};
#pragma unroll
      for (int p = 0; p < 2; ++p)
#pragma unroll
        for (int q = 0; q < 2; ++q)
#pragma unroll
          for (int i = 0; i < 4; ++i)
#pragma unroll
            for (int j = 0; j < 4; ++j)
              acc[p][q][i][j] += a[p][i] * b[q][j];
    }
  }

#pragma unroll
  for (int p = 0; p < 2; ++p) {
#pragma unroll
    for (int i = 0; i < 4; ++i) {
      size_t row = (size_t)tileM + p * 64 + ty * 4 + i;
#pragma unroll
      for (int q = 0; q < 2; ++q) {
        int col = tileN + q * 64 + tx * 4;
        float vv[4];
#pragma unroll
        for (int j = 0; j < 4; ++j) {
          float x = acc[p][q][i][j];
          if (bias) x += bias[col + j];
          if (addend) x += addend[row * 256 + col + j];
          if (relu) x = fmaxf(x, 0.f);
          vv[j] = x;
        }
        if (outmode == 0) {
          // ldco, outcol, col all multiples of 4 -> aligned float4
          *(float4*)&outf[row * ldco + outcol + col] =
              make_float4(vv[0], vv[1], vv[2], vv[3]);
        } else {  // outmode 2: atom head (OUT_STRIDE odd -> scalar stores)
          int mol = (int)(row >> 6), t = (int)(row & 63);
          size_t ob = (size_t)mol * OUT_STRIDE + 4096 + (size_t)t * 128 + col;
          outf[ob + 0] = vv[0]; outf[ob + 1] = vv[1];
          outf[ob + 2] = vv[2]; outf[ob + 3] = vv[3];
        }
      }
    }
  }
}

// ---------------------------------------------------------------------------
// Legacy 64x64 fp32 GEMM (kept only for the tiny N=32 bond-head-2 GEMM).
// ---------------------------------------------------------------------------
template <int AMODE>
__launch_bounds__(256)
__global__ void fgemm(const float* __restrict__ A, const float* __restrict__ A2,
                      const float* __restrict__ B, const float* __restrict__ B2,
                      const float* __restrict__ addend,
                      const float* __restrict__ bias,
                      float* __restrict__ outf,
                      int M, int N, int K, int lda, int ldb, int ldco, int outcol,
                      int relu, int outmode) {
  __shared__ float As[64][17];
  __shared__ float Bs[16][65];
  const int tid = threadIdx.x;
  const int tx = tid & 15, ty = tid >> 4;
  const int tileM = blockIdx.x * 64, tileN = blockIdx.y * 64;
  float acc[4][4] = {};

  const int nkb = (K + 15) >> 4;
  for (int kb = 0; kb < nkb; ++kb) {
    __syncthreads();
    {
      int m = tid >> 2, k0 = (tid & 3) * 4;
      int row = tileM + m;
#pragma unroll
      for (int z = 0; z < 4; ++z) {
        int k = kb * 16 + k0 + z;
        float v = 0.f;
        if (k < K) {
          if (AMODE == 0) v = A[(size_t)row * lda + k];
        }
        As[m][k0 + z] = v;
      }
    }
#pragma unroll
    for (int it = 0; it < 4; ++it) {
      int e = it * 256 + tid;
      int kk = e >> 6, n = e & 63;
      int k = kb * 16 + kk, nn = tileN + n;
      float v = 0.f;
      if (k < K && nn < N) v = B[(size_t)k * ldb + nn];
      Bs[kk][n] = v;
    }
    __syncthreads();
#pragma unroll
    for (int kk = 0; kk < 16; ++kk) {
      float a[4], b[4];
#pragma unroll
      for (int i = 0; i < 4; ++i) a[i] = As[ty * 4 + i][kk];
#pragma unroll
      for (int j = 0; j < 4; ++j) b[j] = Bs[kk][tx * 4 + j];
#pragma unroll
      for (int i = 0; i < 4; ++i)
#pragma unroll
        for (int j = 0; j < 4; ++j) acc[i][j] += a[i] * b[j];
    }
  }

#pragma unroll
  for (int i = 0; i < 4; ++i) {
    size_t row = (size_t)tileM + ty * 4 + i;
#pragma unroll
    for (int j = 0; j < 4; ++j) {
      int col = tileN + tx * 4 + j;
      if (col >= N) continue;
      float v = acc[i][j];
      if (bias) v += bias[col];
      if (relu) v = fmaxf(v, 0.f);
      if (outmode == 0) {
        outf[row * ldco + outcol + col] = v;
      } else if (outmode == 2) {
        int mol = (int)(row >> 6), t = (int)(row & 63);
        outf[(size_t)mol * OUT_STRIDE + 4096 + t * 128 + col] = v;
      } else {  // 3: bond head
        int mol = (int)(row >> 7), u = (int)(row & 127);
        outf[(size_t)mol * OUT_STRIDE + u * 32 + col] = v;
      }
    }
  }
}

// ---------------------------------------------------------------------------
// Fused DMPNN iteration, fp32, in-place h. ONE BLOCK PER MOLECULE (256
// directed edges are rev-closed -> sole reader+writer of its h rows).
// 1024 thr, 256x256 tile, 4 rows x 16 cols per thread (four col-quadrants),
// BK=16, float4 LDS reads (a broadcast, b 2-way free).
// Phase 1: acc = fb@W_i (K=111); mid-relu -> h0 (recomputed, ws too small to
// store h0). Phase 2: acc += m@W_h, m = asumf[src(e)] - h[rev(e)].
// Epilogue: h = relu(acc).
// ---------------------------------------------------------------------------
__launch_bounds__(1024)
__global__ void msg_f(const float* __restrict__ asumf,
                      float* h,
                      const float* __restrict__ Wh,
                      const float* __restrict__ Wi,
                      const float* __restrict__ fb) {
  __shared__ float As[16][260];   // [k][edge], 260*4B = 65*16B aligned rows
  __shared__ float Bs[16][260];   // [k][n]
  const int tid = threadIdx.x;
  const int tx = tid & 15, ty = tid >> 4;  // ty 0..63
  const int mol = blockIdx.x;
  float acc[4][4][4] = {};        // [colquad q][i][j]

  // ---- phase 1: h0 = relu(f_bonds @ W_i), K=111 ----
  for (int kb = 0; kb < 7; ++kb) {
    __syncthreads();
#pragma unroll
    for (int it = 0; it < 4; ++it) {
      int e = it * 1024 + tid;
      int kk = e >> 8, r = e & 255;
      int k = kb * 16 + kk;
      As[kk][r] = (k < 111) ? fb[(size_t)(mol * 256 + r) * 111 + k] : 0.f;
    }
#pragma unroll
    for (int it = 0; it < 4; ++it) {
      int e = it * 1024 + tid;
      int kk = e >> 8, n = e & 255;
      int k = kb * 16 + kk;
      Bs[kk][n] = (k < 111) ? Wi[(size_t)k * 256 + n] : 0.f;
    }
    __syncthreads();
#pragma unroll
    for (int kk = 0; kk < 16; ++kk) {
      const float4 av = *(const float4*)&As[kk][ty * 4];
      const float a[4] = {av.x, av.y, av.z, av.w};
#pragma unroll
      for (int q = 0; q < 4; ++q) {
        const float4 bv = *(const float4*)&Bs[kk][q * 64 + tx * 4];
        const float b[4] = {bv.x, bv.y, bv.z, bv.w};
#pragma unroll
        for (int i = 0; i < 4; ++i)
#pragma unroll
          for (int j = 0; j < 4; ++j) acc[q][i][j] += a[i] * b[j];
      }
    }
  }
  // mid-relu: acc now holds h0
#pragma unroll
  for (int q = 0; q < 4; ++q)
#pragma unroll
    for (int i = 0; i < 4; ++i)
#pragma unroll
      for (int j = 0; j < 4; ++j) acc[q][i][j] = fmaxf(acc[q][i][j], 0.f);

  // ---- phase 2: acc += m @ W_h, K=256 ----
  for (int kb = 0; kb < 16; ++kb) {
    __syncthreads();
#pragma unroll
    for (int it = 0; it < 4; ++it) {
      int e = it * 1024 + tid;
      int kk = e >> 8, r = e & 255;
      int s = e_src(r);
      int rv = (r < 128) ? (r + 128) : (r - 128);
      int k = kb * 16 + kk;
      As[kk][r] = asumf[(size_t)(mol * 64 + s) * 256 + k]
                - h[(size_t)(mol * 256 + rv) * 256 + k];
    }
#pragma unroll
    for (int it = 0; it < 4; ++it) {
      int e = it * 1024 + tid;
      int kk = e >> 8, n = e & 255;
      Bs[kk][n] = Wh[(size_t)(kb * 16 + kk) * 256 + n];
    }
    __syncthreads();
#pragma unroll
    for (int kk = 0; kk < 16; ++kk) {
      const float4 av = *(const float4*)&As[kk][ty * 4];
      const float a[4] = {av.x, av.y, av.z, av.w};
#pragma unroll
      for (int q = 0; q < 4; ++q) {
        const float4 bv = *(const float4*)&Bs[kk][q * 64 + tx * 4];
        const float b[4] = {bv.x, bv.y, bv.z, bv.w};
#pragma unroll
        for (int i = 0; i < 4; ++i)
#pragma unroll
          for (int j = 0; j < 4; ++j) acc[q][i][j] += a[i] * b[j];
      }
    }
  }

  // epilogue: h = relu(acc), float4 stores (in-place safe: all h reads by
  // this block precede the last barrier; other blocks never touch these rows)
#pragma unroll
  for (int i = 0; i < 4; ++i) {
    size_t row = (size_t)mol * 256 + ty * 4 + i;
#pragma unroll
    for (int q = 0; q < 4; ++q) {
      float4 v;
      v.x = fmaxf(acc[q][i][0], 0.f);
      v.y = fmaxf(acc[q][i][1], 0.f);
      v.z = fmaxf(acc[q][i][2], 0.f);
      v.w = fmaxf(acc[q][i][3], 0.f);
      *(float4*)&h[row * 256 + q * 64 + tx * 4] = v;
    }
  }
}

// a_sum over the 4 incoming directed edges of each atom (fp32 h -> fp32 out)
__global__ __launch_bounds__(256) void asum_f(const float* __restrict__ h,
                                              float* __restrict__ out) {
  int g = blockIdx.x * 256 + threadIdx.x;  // 32768 atoms x 64 chunks of 4
  int atom = g >> 6, cc = (g & 63) << 2;
  int mol = atom >> 6, t = atom & 63;
  const float* hb = h + (size_t)mol * ED_PER * HID;
  int e0 = (t + 63) & 63;
  int e1 = 64 + ((t + 62) & 63);
  int e2 = 128 + t;
  int e3 = 192 + t;
  float4 v0 = *(const float4*)(hb + (size_t)e0 * HID + cc);
  float4 v1 = *(const float4*)(hb + (size_t)e1 * HID + cc);
  float4 v2 = *(const float4*)(hb + (size_t)e2 * HID + cc);
  float4 v3 = *(const float4*)(hb + (size_t)e3 * HID + cc);
  float4 o;
  o.x = v0.x + v1.x + v2.x + v3.x;
  o.y = v0.y + v1.y + v2.y + v3.y;
  o.z = v0.z + v1.z + v2.z + v3.z;
  o.w = v0.w + v1.w + v2.w + v3.w;
  *(float4*)(out + (size_t)atom * HID + cc) = o;
}

// flash attention, fp32 I/O: one wave per (mol, head)
__global__ __launch_bounds__(64) void attn_k(const float* __restrict__ qkv,
                                             float* __restrict__ ctx) {
  __shared__ float kls[64 * 32];
  __shared__ float vls[64 * 32];
  int mol = blockIdx.x >> 3, head = blockIdx.x & 7;
  int lane = threadIdx.x;
  size_t rb = ((size_t)(mol * 64 + lane)) * 768 + head * 32;
#pragma unroll
  for (int c = 0; c < 8; ++c) {
    *(float4*)(kls + lane * 32 + c * 4) = *(const float4*)(qkv + rb + 256 + c * 4);
    *(float4*)(vls + lane * 32 + c * 4) = *(const float4*)(qkv + rb + 512 + c * 4);
  }
  float q[32];
#pragma unroll
  for (int d = 0; d < 32; ++d) q[d] = qkv[rb + d];
  __syncthreads();
  float mx = -1e30f, l = 0.f;
  float acc[32];
#pragma unroll
  for (int d = 0; d < 32; ++d) acc[d] = 0.f;
  for (int j = 0; j < 64; ++j) {
    float s = 0.f;
#pragma unroll
    for (int d = 0; d < 32; ++d) s += q[d] * kls[j * 32 + d];
    s *= 0.17677669529663687f;  // 1/sqrt(32)
    float nm = fmaxf(mx, s);
    float co = __expf(mx - nm);
    float p = __expf(s - nm);
    l = l * co + p;
#pragma unroll
    for (int d = 0; d < 32; ++d) acc[d] = acc[d] * co + p * vls[j * 32 + d];
    mx = nm;
  }
  float inv = 1.f / l;
  float* op = ctx + ((size_t)(mol * 64 + lane)) * 256 + head * 32;
#pragma unroll
  for (int d = 0; d < 32; ++d) op[d] = acc[d] * inv;
}

// graph_vecs[mol][c] = sum over 64 atoms
__global__ __launch_bounds__(256) void gv_k(const float* __restrict__ af, float* __restrict__ gv) {
  int mol = blockIdx.x, c = threadIdx.x;
  float s = 0.f;
  for (int a = 0; a < 64; ++a) s += af[((size_t)mol * 64 + a) * HID + c];
  gv[mol * HID + c] = s;
}

// graph head: relu(gv@G1+g1)@G2+g2 -> out[mol*12289+12288]
__global__ __launch_bounds__(512) void gh_k(const float* __restrict__ gv, const float* __restrict__ G1,
                                            const float* __restrict__ g1, const float* __restrict__ G2,
                                            const float* __restrict__ g2, float* __restrict__ out) {
  __shared__ float xs[256];
  __shared__ float red[512];
  int mol = blockIdx.x, j = threadIdx.x;
  if (j < 256) xs[j] = gv[mol * 256 + j];
  __syncthreads();
  float s = 0.f;
  for (int k = 0; k < 256; ++k) s += xs[k] * G1[k * 512 + j];
  s = fmaxf(s + g1[j], 0.f);
  red[j] = s * G2[j];
  __syncthreads();
  for (int st = 256; st > 0; st >>= 1) {
    if (j < st) red[j] += red[j + st];
    __syncthreads();
  }
  if (j == 0) out[(size_t)mol * OUT_STRIDE + 12288] = red[0] + g2[0];
}

extern "C" void kernel_launch(void* const* d_in, const int* in_sizes, int n_in,
                              void* d_out, int out_size, void* d_ws, size_t ws_size,
                              hipStream_t stream) {
  (void)in_sizes; (void)n_in; (void)out_size; (void)ws_size;
  const float* f_atoms  = (const float*)d_in[0];
  const float* f_bonds  = (const float*)d_in[1];
  const float* prev_hid = (const float*)d_in[2];
  const float* W_i   = (const float*)d_in[7];
  const float* W_h   = (const float*)d_in[8];
  const float* W_o   = (const float*)d_in[9];
  const float* b_o   = (const float*)d_in[10];
  const float* Wq    = (const float*)d_in[11];
  const float* Wk    = (const float*)d_in[12];
  const float* Wv    = (const float*)d_in[13];
  const float* Wattn = (const float*)d_in[14];
  const float* W_vv  = (const float*)d_in[15];
  const float* W_vc  = (const float*)d_in[16];
  const float* A1    = (const float*)d_in[17];
  const float* a1    = (const float*)d_in[18];
  const float* A2    = (const float*)d_in[19];
  const float* a2    = (const float*)d_in[20];
  const float* B1    = (const float*)d_in[21];
  const float* b1    = (const float*)d_in[22];
  const float* B2    = (const float*)d_in[23];
  const float* b2b   = (const float*)d_in[24];
  const float* G1    = (const float*)d_in[25];
  const float* g1    = (const float*)d_in[26];
  const float* G2    = (const float*)d_in[27];
  const float* g2    = (const float*)d_in[28];
  float* out = (float*)d_out;

  // ---- fp32 workspace, 168.3 MB total (< known-good 187.3) ----
  char* base = (char*)d_ws;
  float* h     = (float*)(base);                    // [0, 134217728)  h fp32
  float* asumf = (float*)(base + 134217728);        // [134.2M, 167.8M)
  float* gvec  = (float*)(base + 167772160);        // 0.5 MB
  // post-loop aliases (sequential-stream lifetimes audited):
  float* xA    = (float*)(base);                    // 33.5 MB  a_feats (step 4-7)
  float* qkv   = (float*)(base + 33554432);         // 100.7 MB (step 5-6)
  float* ctx   = (float*)(base + 134217728);        // 33.5 MB  (step 6-7, over dead asumf)
  float* afat  = (float*)(base + 33554432);         // 33.5 MB  (step 7-8, over dead qkv)
  float* atomf = (float*)(base + 134217728);        // 33.5 MB  (step 8-end, over dead ctx)
  float* t1    = (float*)(base);                    // 67.1 MB  (step 9)
  float* t2    = (float*)(base);                    // 134.2 MB (step 10)

  // 1) h = h0 = relu(f_bonds @ W_i)
  fgemm128<0><<<dim3(1024, 2), 256, 0, stream>>>(
      f_bonds, nullptr, W_i, nullptr, nullptr, nullptr, h,
      N_DIR, 256, 111, 111, 256, 256, 0, 1, 0);

  // 2) DMPNN loop, fully fp32, in-place h (one block per molecule)
  for (int d = 0; d < 9; ++d) {
    asum_f<<<8192, 256, 0, stream>>>(h, asumf);
    msg_f<<<512, 1024, 0, stream>>>(asumf, h, W_h, W_i, f_bonds);
  }

  // 3) a_in
  asum_f<<<8192, 256, 0, stream>>>(h, asumf);
  // 4) a_feats = relu([f_atoms | a_in] @ W_o + b_o)
  fgemm128<2><<<dim3(256, 2), 256, 0, stream>>>(
      asumf, f_atoms, W_o, nullptr, nullptr, b_o, xA,
      N_ATOMS, 256, 354, 0, 256, 256, 0, 1, 0);
  // 5) qkv
  fgemm128<0><<<dim3(256, 2), 256, 0, stream>>>(
      xA, nullptr, Wq, nullptr, nullptr, nullptr, qkv,
      N_ATOMS, 256, 256, 256, 256, 768, 0, 0, 0);
  fgemm128<0><<<dim3(256, 2), 256, 0, stream>>>(
      xA, nullptr, Wk, nullptr, nullptr, nullptr, qkv,
      N_ATOMS, 256, 256, 256, 256, 768, 256, 0, 0);
  fgemm128<0><<<dim3(256, 2), 256, 0, stream>>>(
      xA, nullptr, Wv, nullptr, nullptr, nullptr, qkv,
      N_ATOMS, 256, 256, 256, 256, 768, 512, 0, 0);
  // 6) attention
  attn_k<<<4096, 64, 0, stream>>>(qkv, ctx);
  // 7) a_feats' = x + ctx @ Wattn
  fgemm128<0><<<dim3(256, 2), 256, 0, stream>>>(
      ctx, nullptr, Wattn, nullptr, xA, nullptr, afat,
      N_ATOMS, 256, 256, 256, 256, 256, 0, 0, 0);
  // 8) atom_feats = relu(afat @ W_vc^T + prev_hid @ W_vv^T)
  fgemm128<3><<<dim3(256, 2), 256, 0, stream>>>(
      afat, prev_hid, W_vc, W_vv, nullptr, nullptr, atomf,
      N_ATOMS, 256, 512, 0, 0, 256, 0, 1, 0);
  // 9) atom head
  fgemm128<0><<<dim3(256, 4), 256, 0, stream>>>(
      atomf, nullptr, A1, nullptr, nullptr, a1, t1,
      N_ATOMS, 512, 256, 256, 512, 512, 0, 1, 0);
  fgemm128<0><<<dim3(256, 1), 256, 0, stream>>>(
      t1, nullptr, A2, nullptr, nullptr, a2, out,
      N_ATOMS, 128, 512, 512, 128, 0, 0, 0, 2);
  // 10) bond head
  fgemm128<4><<<dim3(512, 4), 256, 0, stream>>>(
      atomf, nullptr, B1, nullptr, nullptr, b1, t2,
      N_UND, 512, 512, 0, 512, 512, 0, 1, 0);
  fgemm<0><<<dim3(1024, 1), 256, 0, stream>>>(
      t2, nullptr, B2, nullptr, nullptr, b2b, out,
      N_UND, 32, 512, 512, 32, 0, 0, 0, 3);
  // 11) graph head
  gv_k<<<512, 256, 0, stream>>>(atomf, gvec);
  gh_k<<<512, 512, 0, stream>>>(gvec, G1, g1, G2, g2, out);
}

// Round 2
// 2143.759 us; speedup vs baseline: 4.1938x; 4.1938x over previous
//
#include <hip/hip_runtime.h>
#include <cstdint>
#include <cstddef>

#define B_MOL 512
#define A_PER 64
#define ED_PER 256
#define N_ATOMS (B_MOL * A_PER)   // 32768
#define N_DIR (B_MOL * ED_PER)    // 131072
#define N_UND (B_MOL * 128)       // 65536
#define HID 256
#define OUT_STRIDE 12289
#define AP 40   // LDS pitch (shorts) for a 32-wide k row: 32 + 8 pad -> 2-way banks

typedef __attribute__((ext_vector_type(8))) short bf16x8;
typedef __attribute__((ext_vector_type(8))) unsigned short u16x8;
typedef __attribute__((ext_vector_type(4))) float f32x4;

#define MFMA(a, b, c) __builtin_amdgcn_mfma_f32_16x16x32_bf16(a, b, c, 0, 0, 0)

__device__ __forceinline__ float b2f(unsigned short s) {
  return __builtin_bit_cast(float, (unsigned)s << 16);
}
// split fp32 -> (hi, lo) bf16 planes: x ~= hi + lo, |err| <~ 2^-16 |x|
__device__ __forceinline__ void split2(float v, unsigned short& h, unsigned short& l) {
  unsigned ub = __builtin_bit_cast(unsigned, v);
  h = (unsigned short)(ub >> 16);
  float fh = __builtin_bit_cast(float, ub & 0xffff0000u);
  float r = v - fh;
  l = (unsigned short)(__builtin_bit_cast(unsigned, r) >> 16);
}
__device__ __forceinline__ int e_src(int e) {
  return (e < 64) ? e : (e < 128) ? (e - 64)
       : (e < 192) ? ((e - 127) & 63) : ((e - 190) & 63);
}

// ---------------------------------------------------------------------------
// Weight pre-convert: dst[n][k] (two bf16 planes, pitch Kp) from fp32 src.
// mode 0: transpose  dst[n][k] = src[k*N + n]            (k < K, else 0)
// mode 1: W_o remap  dst[n][k] = W_o[98+k][n] (k<256) | W_o[k-256][n] (k<354)
// mode 2: vcvv       dst[n][k] = src[n*256+k] (k<256) | src2[n*256+k-256]
// ---------------------------------------------------------------------------
__global__ __launch_bounds__(256) void convT(const float* __restrict__ src,
                                             const float* __restrict__ src2,
                                             unsigned short* __restrict__ dh,
                                             unsigned short* __restrict__ dl,
                                             int K, int N, int Kp, int mode) {
  int n = blockIdx.x;
  for (int k = threadIdx.x; k < Kp; k += 256) {
    float v = 0.f;
    if (mode == 0) {
      if (k < K) v = src[(size_t)k * N + n];
    } else if (mode == 1) {
      if (k < 256) v = src[(size_t)(98 + k) * 256 + n];
      else if (k < 354) v = src[(size_t)(k - 256) * 256 + n];
    } else {
      if (k < 256) v = src[(size_t)n * 256 + k];
      else v = src2[(size_t)n * 256 + (k - 256)];
    }
    unsigned short h_, l_;
    split2(v, h_, l_);
    dh[(size_t)n * Kp + k] = h_;
    dl[(size_t)n * Kp + k] = l_;
  }
}

// ---------------------------------------------------------------------------
// mgemm: split-bf16 MFMA GEMM. 128x128 tile, BK=32, 256 thr (4 waves, 2x2),
// 64x64/wave = 16 frags of 16x16x32, 3 MFMA per frag-pair (hi*hi+hi*lo+lo*hi).
// B always pre-split/pre-transposed global [N][Kp] planes (BTh/BTl, ldb=Kp).
// AMODE 0: fp32 A [M][lda], stage-convert.
//       1: split A planes (Aa=hi, Ab=lo, lda = pitch, K%32==0).
//       2: concat fp32: k<256 asumF(Aa), k<354 f_atoms(Ab)[row*98+k-256].
//       3: k<256 split afat (Aa/Ab), k>=256 fp32 prev_hid (Ac)[row*256+k-256].
//       4: bond gather from split atomf planes (Aa/Ab), K=512.
// outmode 0: split planes (outA=hi, outB=lo, pitch ldco)
//         1: fp32 (outA, pitch ldco, +outcol)
//         2: atom-head strided fp32   3: bond-head strided fp32
// ---------------------------------------------------------------------------
template <int AMODE>
__launch_bounds__(256, 3)
__global__ void mgemm(const void* Aa_, const void* Ab_, const void* Ac_,
                      const unsigned short* __restrict__ BTh,
                      const unsigned short* __restrict__ BTl, int ldb,
                      const unsigned short* addH, const unsigned short* addL,
                      const float* __restrict__ bias,
                      void* outA, void* outB,
                      int M, int N, int K, int lda, int ldco, int outcol,
                      int relu, int outmode) {
  __shared__ unsigned short AsH[128 * AP], AsL[128 * AP];
  __shared__ unsigned short BsH[128 * AP], BsL[128 * AP];
  const int tid = threadIdx.x;
  const int lane = tid & 63;
  const int l15 = lane & 15, l4 = lane >> 4;
  const int w = tid >> 6;
  const int wr = (w >> 1) * 64, wc = (w & 1) * 64;
  const int tileM = blockIdx.x * 128, tileN = blockIdx.y * 128;
  const int srow = tid >> 1;           // staging row 0..127
  const int sks = (tid & 1) * 16;      // staging k-seg {0,16}

  int rem = N - tileN - wc;
  int bnMax = rem >= 64 ? 4 : (rem > 0 ? (rem >> 4) : 0);

  f32x4 zf = {0.f, 0.f, 0.f, 0.f};
  f32x4 acc[4][4];
#pragma unroll
  for (int i = 0; i < 4; ++i)
#pragma unroll
    for (int j = 0; j < 4; ++j) acc[i][j] = zf;

  const int nkb = (K + 31) >> 5;
  for (int kb = 0; kb < nkb; ++kb) {
    __syncthreads();
    const int k0 = kb * 32 + sks;
    // ---- stage A (16 elems: row tileM+srow, k = k0..k0+15) ----
    {
      const int row = tileM + srow;
      if (AMODE == 1 || AMODE == 4 || (AMODE == 3 && k0 < 256)) {
        const unsigned short* Ah = (const unsigned short*)Aa_;
        const unsigned short* Al = (const unsigned short*)Ab_;
        size_t bse;
        if (AMODE == 4) {
          int mol = row >> 7, u = row & 127;
          int a0 = (u < 64) ? u : (u - 64);
          int a1 = (u < 64) ? ((u + 1) & 63) : ((u - 62) & 63);
          int atom = (k0 < 256) ? a0 : a1;
          bse = (size_t)(mol * 64 + atom) * 256 + (k0 & 255);
        } else if (AMODE == 3) {
          bse = (size_t)row * 256 + k0;
        } else {
          bse = (size_t)row * lda + k0;
        }
        *(u16x8*)&AsH[srow * AP + sks]     = *(const u16x8*)&Ah[bse];
        *(u16x8*)&AsH[srow * AP + sks + 8] = *(const u16x8*)&Ah[bse + 8];
        *(u16x8*)&AsL[srow * AP + sks]     = *(const u16x8*)&Al[bse];
        *(u16x8*)&AsL[srow * AP + sks + 8] = *(const u16x8*)&Al[bse + 8];
      } else {
        u16x8 hv0 = {0,0,0,0,0,0,0,0}, lv0 = {0,0,0,0,0,0,0,0};
        u16x8 hv1 = {0,0,0,0,0,0,0,0}, lv1 = {0,0,0,0,0,0,0,0};
#pragma unroll
        for (int z = 0; z < 16; ++z) {
          int k = k0 + z;
          float v = 0.f;
          if (AMODE == 0) {
            if (k < K) v = ((const float*)Aa_)[(size_t)row * lda + k];
          } else if (AMODE == 2) {
            if (k < 256) v = ((const float*)Aa_)[(size_t)row * 256 + k];
            else if (k < 354) v = ((const float*)Ab_)[(size_t)row * 98 + (k - 256)];
          } else {  // AMODE 3, k0 >= 256
            v = ((const float*)Ac_)[(size_t)row * 256 + (k - 256)];
          }
          unsigned short h_, l_;
          split2(v, h_, l_);
          if (z < 8) { hv0[z] = h_; lv0[z] = l_; }
          else       { hv1[z - 8] = h_; lv1[z - 8] = l_; }
        }
        *(u16x8*)&AsH[srow * AP + sks]     = hv0;
        *(u16x8*)&AsH[srow * AP + sks + 8] = hv1;
        *(u16x8*)&AsL[srow * AP + sks]     = lv0;
        *(u16x8*)&AsL[srow * AP + sks + 8] = lv1;
      }
    }
    // ---- stage B (16 elems: n tileN+srow, k = k0..k0+15) ----
    {
      const int n = tileN + srow;
      if (n < N) {
        size_t bb = (size_t)n * ldb + k0;
        *(u16x8*)&BsH[srow * AP + sks]     = *(const u16x8*)&BTh[bb];
        *(u16x8*)&BsH[srow * AP + sks + 8] = *(const u16x8*)&BTh[bb + 8];
        *(u16x8*)&BsL[srow * AP + sks]     = *(const u16x8*)&BTl[bb];
        *(u16x8*)&BsL[srow * AP + sks + 8] = *(const u16x8*)&BTl[bb + 8];
      } else {
        u16x8 z8 = {0,0,0,0,0,0,0,0};
        *(u16x8*)&BsH[srow * AP + sks]     = z8;
        *(u16x8*)&BsH[srow * AP + sks + 8] = z8;
        *(u16x8*)&BsL[srow * AP + sks]     = z8;
        *(u16x8*)&BsL[srow * AP + sks + 8] = z8;
      }
    }
    __syncthreads();
    // ---- compute ----
    bf16x8 ah[4], al[4];
#pragma unroll
    for (int am = 0; am < 4; ++am) {
      int ar = wr + am * 16 + l15;
      ah[am] = *(const bf16x8*)&AsH[ar * AP + l4 * 8];
      al[am] = *(const bf16x8*)&AsL[ar * AP + l4 * 8];
    }
#pragma unroll
    for (int bn = 0; bn < 4; ++bn) {
      if (bn < bnMax) {
        int br = wc + bn * 16 + l15;
        bf16x8 bh = *(const bf16x8*)&BsH[br * AP + l4 * 8];
        bf16x8 bl = *(const bf16x8*)&BsL[br * AP + l4 * 8];
#pragma unroll
        for (int am = 0; am < 4; ++am) {
          acc[am][bn] = MFMA(ah[am], bh, acc[am][bn]);
          acc[am][bn] = MFMA(ah[am], bl, acc[am][bn]);
          acc[am][bn] = MFMA(al[am], bh, acc[am][bn]);
        }
      }
    }
  }

  // ---- epilogue ----
#pragma unroll
  for (int am = 0; am < 4; ++am) {
#pragma unroll
    for (int bn = 0; bn < 4; ++bn) {
      if (bn >= bnMax) continue;
      int col = tileN + wc + bn * 16 + l15;
      float bs = bias ? bias[col] : 0.f;
#pragma unroll
      for (int r = 0; r < 4; ++r) {
        size_t row = (size_t)tileM + wr + am * 16 + l4 * 4 + r;
        float v = acc[am][bn][r] + bs;
        if (addH) v += b2f(addH[row * 256 + col]) + b2f(addL[row * 256 + col]);
        if (relu) v = fmaxf(v, 0.f);
        if (outmode == 0) {
          unsigned short h_, l_;
          split2(v, h_, l_);
          ((unsigned short*)outA)[row * (size_t)ldco + col] = h_;
          ((unsigned short*)outB)[row * (size_t)ldco + col] = l_;
        } else if (outmode == 1) {
          ((float*)outA)[row * (size_t)ldco + outcol + col] = v;
        } else if (outmode == 2) {
          int mol = (int)(row >> 6), t = (int)(row & 63);
          ((float*)outA)[(size_t)mol * OUT_STRIDE + 4096 + t * 128 + col] = v;
        } else {
          int mol = (int)(row >> 7), u = (int)(row & 127);
          ((float*)outA)[(size_t)mol * OUT_STRIDE + u * 32 + col] = v;
        }
      }
    }
  }
}

// ---------------------------------------------------------------------------
// Fused DMPNN iteration, split-bf16 MFMA, in-place split h planes.
// Block = rev-closed 128-edge set of one molecule (tT: {0-63,128-191} or
// {64-127,192-255}) x N=256. 512 thr = 8 waves (4M x 2N), 32x128/wave,
// 2x8 frags. Phase 1: acc = fb@Wi (K=111, stage-convert); mid-relu -> h0.
// Phase 2: acc += (asum[src] - h[rev]) @ Wh. Epilogue: h = relu(acc), split.
// ---------------------------------------------------------------------------
__launch_bounds__(512, 4)
__global__ void msg_m(const float* __restrict__ asumF,
                      unsigned short* hH, unsigned short* hL,
                      const unsigned short* __restrict__ WhTh,
                      const unsigned short* __restrict__ WhTl,
                      const unsigned short* __restrict__ WiTh,
                      const unsigned short* __restrict__ WiTl,
                      const float* __restrict__ fb) {
  __shared__ unsigned short AsH[128 * AP], AsL[128 * AP];
  __shared__ unsigned short BsH[256 * AP], BsL[256 * AP];
  const int tid = threadIdx.x;
  const int lane = tid & 63;
  const int l15 = lane & 15, l4 = lane >> 4;
  const int w = tid >> 6;          // 0..7
  const int wm = (w >> 1) * 32;    // row base (of 128)
  const int wn = (w & 1) * 128;    // col base (of 256)
  const int mol = blockIdx.x >> 1, tT = blockIdx.x & 1;
  const int arow = tid >> 2, aks = (tid & 3) * 8;   // A stage: 8 elems
  const int bnr = tid >> 1, bks = (tid & 1) * 16;   // B stage: 16 elems

  f32x4 zf = {0.f, 0.f, 0.f, 0.f};
  f32x4 acc[2][8];
#pragma unroll
  for (int i = 0; i < 2; ++i)
#pragma unroll
    for (int j = 0; j < 8; ++j) acc[i][j] = zf;

  const int eA = 64 * tT + arow + (arow & 64);  // staged edge id (rev-closed map)

  // ---- phase 1: h0 = relu(fb @ Wi), K=111 (4 k-steps) ----
  for (int kb = 0; kb < 4; ++kb) {
    __syncthreads();
    {
      size_t fbb = (size_t)(mol * 256 + eA) * 111;
      u16x8 hv = {0,0,0,0,0,0,0,0}, lv = {0,0,0,0,0,0,0,0};
#pragma unroll
      for (int z = 0; z < 8; ++z) {
        int k = kb * 32 + aks + z;
        float v = (k < 111) ? fb[fbb + k] : 0.f;
        unsigned short h_, l_;
        split2(v, h_, l_);
        hv[z] = h_; lv[z] = l_;
      }
      *(u16x8*)&AsH[arow * AP + aks] = hv;
      *(u16x8*)&AsL[arow * AP + aks] = lv;
    }
    {
      size_t bb = (size_t)bnr * 128 + kb * 32 + bks;
      *(u16x8*)&BsH[bnr * AP + bks]     = *(const u16x8*)&WiTh[bb];
      *(u16x8*)&BsH[bnr * AP + bks + 8] = *(const u16x8*)&WiTh[bb + 8];
      *(u16x8*)&BsL[bnr * AP + bks]     = *(const u16x8*)&WiTl[bb];
      *(u16x8*)&BsL[bnr * AP + bks + 8] = *(const u16x8*)&WiTl[bb + 8];
    }
    __syncthreads();
    bf16x8 ah[2], al[2];
#pragma unroll
    for (int am = 0; am < 2; ++am) {
      int ar = wm + am * 16 + l15;
      ah[am] = *(const bf16x8*)&AsH[ar * AP + l4 * 8];
      al[am] = *(const bf16x8*)&AsL[ar * AP + l4 * 8];
    }
#pragma unroll
    for (int bn = 0; bn < 8; ++bn) {
      int br = wn + bn * 16 + l15;
      bf16x8 bh = *(const bf16x8*)&BsH[br * AP + l4 * 8];
      bf16x8 bl = *(const bf16x8*)&BsL[br * AP + l4 * 8];
#pragma unroll
      for (int am = 0; am < 2; ++am) {
        acc[am][bn] = MFMA(ah[am], bh, acc[am][bn]);
        acc[am][bn] = MFMA(ah[am], bl, acc[am][bn]);
        acc[am][bn] = MFMA(al[am], bh, acc[am][bn]);
      }
    }
  }
  // mid-relu -> acc holds h0
#pragma unroll
  for (int i = 0; i < 2; ++i)
#pragma unroll
    for (int j = 0; j < 8; ++j)
#pragma unroll
      for (int r = 0; r < 4; ++r) acc[i][j][r] = fmaxf(acc[i][j][r], 0.f);

  // ---- phase 2: acc += (asum[src] - h[rev]) @ Wh, K=256 (8 k-steps) ----
  {
    const int sA = e_src(eA);
    const int rvA = (eA < 128) ? (eA + 128) : (eA - 128);
    const float* apb = &asumF[(size_t)(mol * 64 + sA) * 256];
    const size_t hrb = (size_t)(mol * 256 + rvA) * 256;
    for (int kb = 0; kb < 8; ++kb) {
      __syncthreads();
      {
        int k0 = kb * 32 + aks;
        u16x8 hh = *(const u16x8*)&hH[hrb + k0];
        u16x8 hl = *(const u16x8*)&hL[hrb + k0];
        u16x8 hv = {0,0,0,0,0,0,0,0}, lv = {0,0,0,0,0,0,0,0};
#pragma unroll
        for (int z = 0; z < 8; ++z) {
          float m = apb[k0 + z] - b2f(hh[z]) - b2f(hl[z]);
          unsigned short h_, l_;
          split2(m, h_, l_);
          hv[z] = h_; lv[z] = l_;
        }
        *(u16x8*)&AsH[arow * AP + aks] = hv;
        *(u16x8*)&AsL[arow * AP + aks] = lv;
      }
      {
        size_t bb = (size_t)bnr * 256 + kb * 32 + bks;
        *(u16x8*)&BsH[bnr * AP + bks]     = *(const u16x8*)&WhTh[bb];
        *(u16x8*)&BsH[bnr * AP + bks + 8] = *(const u16x8*)&WhTh[bb + 8];
        *(u16x8*)&BsL[bnr * AP + bks]     = *(const u16x8*)&WhTl[bb];
        *(u16x8*)&BsL[bnr * AP + bks + 8] = *(const u16x8*)&WhTl[bb + 8];
      }
      __syncthreads();
      bf16x8 ah[2], al[2];
#pragma unroll
      for (int am = 0; am < 2; ++am) {
        int ar = wm + am * 16 + l15;
        ah[am] = *(const bf16x8*)&AsH[ar * AP + l4 * 8];
        al[am] = *(const bf16x8*)&AsL[ar * AP + l4 * 8];
      }
#pragma unroll
      for (int bn = 0; bn < 8; ++bn) {
        int br = wn + bn * 16 + l15;
        bf16x8 bh = *(const bf16x8*)&BsH[br * AP + l4 * 8];
        bf16x8 bl = *(const bf16x8*)&BsL[br * AP + l4 * 8];
#pragma unroll
        for (int am = 0; am < 2; ++am) {
          acc[am][bn] = MFMA(ah[am], bh, acc[am][bn]);
          acc[am][bn] = MFMA(ah[am], bl, acc[am][bn]);
          acc[am][bn] = MFMA(al[am], bh, acc[am][bn]);
        }
      }
    }
  }

  // ---- epilogue: h = relu(acc), split, in-place (all h reads done pre-barrier)
#pragma unroll
  for (int am = 0; am < 2; ++am) {
#pragma unroll
    for (int r = 0; r < 4; ++r) {
      int rl = wm + am * 16 + l4 * 4 + r;
      int e = 64 * tT + rl + (rl & 64);
      size_t rowb = (size_t)(mol * 256 + e) * 256;
#pragma unroll
      for (int bn = 0; bn < 8; ++bn) {
        int col = wn + bn * 16 + l15;
        float v = fmaxf(acc[am][bn][r], 0.f);
        unsigned short h_, l_;
        split2(v, h_, l_);
        hH[rowb + col] = h_;
        hL[rowb + col] = l_;
      }
    }
  }
}

// a_sum over 4 incoming directed edges (split h planes -> fp32 out)
__global__ __launch_bounds__(256) void asum_f(const unsigned short* __restrict__ hHp,
                                              const unsigned short* __restrict__ hLp,
                                              float* __restrict__ out) {
  int g = blockIdx.x * 256 + threadIdx.x;  // 32768 atoms x 32 chunks of 8
  int atom = g >> 5, cc = (g & 31) << 3;
  int mol = atom >> 6, t = atom & 63;
  size_t hb = (size_t)mol * 256 * 256;
  int e0 = (t + 63) & 63;
  int e1 = 64 + ((t + 62) & 63);
  int e2 = 128 + t;
  int e3 = 192 + t;
  float s0=0,s1=0,s2=0,s3=0,s4=0,s5=0,s6=0,s7=0;
#define ACC_E(ee) { \
    u16x8 vh = *(const u16x8*)&hHp[hb + (size_t)(ee) * 256 + cc]; \
    u16x8 vl = *(const u16x8*)&hLp[hb + (size_t)(ee) * 256 + cc]; \
    s0 += b2f(vh[0]) + b2f(vl[0]); s1 += b2f(vh[1]) + b2f(vl[1]); \
    s2 += b2f(vh[2]) + b2f(vl[2]); s3 += b2f(vh[3]) + b2f(vl[3]); \
    s4 += b2f(vh[4]) + b2f(vl[4]); s5 += b2f(vh[5]) + b2f(vl[5]); \
    s6 += b2f(vh[6]) + b2f(vl[6]); s7 += b2f(vh[7]) + b2f(vl[7]); }
  ACC_E(e0); ACC_E(e1); ACC_E(e2); ACC_E(e3);
#undef ACC_E
  float4 o0 = {s0, s1, s2, s3}, o1 = {s4, s5, s6, s7};
  *(float4*)&out[(size_t)atom * 256 + cc] = o0;
  *(float4*)&out[(size_t)atom * 256 + cc + 4] = o1;
}

// flash attention, fp32 qkv in, split ctx out: one wave per (mol, head)
__global__ __launch_bounds__(64) void attn_k(const float* __restrict__ qkv,
                                             unsigned short* __restrict__ ctxH,
                                             unsigned short* __restrict__ ctxL) {
  __shared__ float kls[64 * 32];
  __shared__ float vls[64 * 32];
  int mol = blockIdx.x >> 3, head = blockIdx.x & 7;
  int lane = threadIdx.x;
  size_t rb = ((size_t)(mol * 64 + lane)) * 768 + head * 32;
#pragma unroll
  for (int c = 0; c < 8; ++c) {
    *(float4*)(kls + lane * 32 + c * 4) = *(const float4*)(qkv + rb + 256 + c * 4);
    *(float4*)(vls + lane * 32 + c * 4) = *(const float4*)(qkv + rb + 512 + c * 4);
  }
  float q[32];
#pragma unroll
  for (int d = 0; d < 32; ++d) q[d] = qkv[rb + d];
  __syncthreads();
  float mx = -1e30f, l = 0.f;
  float acc[32];
#pragma unroll
  for (int d = 0; d < 32; ++d) acc[d] = 0.f;
  for (int j = 0; j < 64; ++j) {
    float s = 0.f;
#pragma unroll
    for (int d = 0; d < 32; ++d) s += q[d] * kls[j * 32 + d];
    s *= 0.17677669529663687f;  // 1/sqrt(32)
    float nm = fmaxf(mx, s);
    float co = __expf(mx - nm);
    float p = __expf(s - nm);
    l = l * co + p;
#pragma unroll
    for (int d = 0; d < 32; ++d) acc[d] = acc[d] * co + p * vls[j * 32 + d];
    mx = nm;
  }
  float inv = 1.f / l;
  size_t ob = ((size_t)(mol * 64 + lane)) * 256 + head * 32;
#pragma unroll
  for (int d = 0; d < 32; ++d) {
    unsigned short h_, l_;
    split2(acc[d] * inv, h_, l_);
    ctxH[ob + d] = h_;
    ctxL[ob + d] = l_;
  }
}

// graph_vecs[mol][c] = sum over 64 atoms (split atomf planes)
__global__ __launch_bounds__(256) void gv_k(const unsigned short* __restrict__ afH,
                                            const unsigned short* __restrict__ afL,
                                            float* __restrict__ gv) {
  int mol = blockIdx.x, c = threadIdx.x;
  float s = 0.f;
  for (int a = 0; a < 64; ++a) {
    size_t i = ((size_t)mol * 64 + a) * 256 + c;
    s += b2f(afH[i]) + b2f(afL[i]);
  }
  gv[mol * 256 + c] = s;
}

// graph head: relu(gv@G1+g1)@G2+g2 -> out[mol*12289+12288]
__global__ __launch_bounds__(512) void gh_k(const float* __restrict__ gv, const float* __restrict__ G1,
                                            const float* __restrict__ g1, const float* __restrict__ G2,
                                            const float* __restrict__ g2, float* __restrict__ out) {
  __shared__ float xs[256];
  __shared__ float red[512];
  int mol = blockIdx.x, j = threadIdx.x;
  if (j < 256) xs[j] = gv[mol * 256 + j];
  __syncthreads();
  float s = 0.f;
  for (int k = 0; k < 256; ++k) s += xs[k] * G1[k * 512 + j];
  s = fmaxf(s + g1[j], 0.f);
  red[j] = s * G2[j];
  __syncthreads();
  for (int st = 256; st > 0; st >>= 1) {
    if (j < st) red[j] += red[j + st];
    __syncthreads();
  }
  if (j == 0) out[(size_t)mol * OUT_STRIDE + 12288] = red[0] + g2[0];
}

extern "C" void kernel_launch(void* const* d_in, const int* in_sizes, int n_in,
                              void* d_out, int out_size, void* d_ws, size_t ws_size,
                              hipStream_t stream) {
  (void)in_sizes; (void)n_in; (void)out_size; (void)ws_size;
  const float* f_atoms  = (const float*)d_in[0];
  const float* f_bonds  = (const float*)d_in[1];
  const float* prev_hid = (const float*)d_in[2];
  const float* W_i   = (const float*)d_in[7];
  const float* W_h   = (const float*)d_in[8];
  const float* W_o   = (const float*)d_in[9];
  const float* b_o   = (const float*)d_in[10];
  const float* Wq    = (const float*)d_in[11];
  const float* Wk    = (const float*)d_in[12];
  const float* Wv    = (const float*)d_in[13];
  const float* Wattn = (const float*)d_in[14];
  const float* W_vc  = (const float*)d_in[15 + 1];
  const float* W_vv  = (const float*)d_in[15];
  const float* A1    = (const float*)d_in[17];
  const float* a1    = (const float*)d_in[18];
  const float* A2    = (const float*)d_in[19];
  const float* a2    = (const float*)d_in[20];
  const float* B1    = (const float*)d_in[21];
  const float* b1    = (const float*)d_in[22];
  const float* B2    = (const float*)d_in[23];
  const float* b2b   = (const float*)d_in[24];
  const float* G1    = (const float*)d_in[25];
  const float* g1    = (const float*)d_in[26];
  const float* G2    = (const float*)d_in[27];
  const float* g2    = (const float*)d_in[28];
  float* out = (float*)d_out;

  // ---- workspace (172.6 MB < known-good 187.3) ----
  char* base = (char*)d_ws;
  unsigned short* hH = (unsigned short*)(base);                // 67.1 MB
  unsigned short* hL = (unsigned short*)(base + 67108864);     // 67.1 MB
  float* asumF = (float*)(base + 134217728);                   // 33.6 MB
  char* W0 = base + 167772160;                                 // weights ~4.8 MB
  unsigned short* WiTh = (unsigned short*)(W0);
  unsigned short* WiTl = (unsigned short*)(W0 + 65536);
  unsigned short* WhTh = (unsigned short*)(W0 + 131072);
  unsigned short* WhTl = (unsigned short*)(W0 + 262144);
  unsigned short* WoTh = (unsigned short*)(W0 + 393216);
  unsigned short* WoTl = (unsigned short*)(W0 + 589824);
  unsigned short* WqTh = (unsigned short*)(W0 + 786432);
  unsigned short* WqTl = (unsigned short*)(W0 + 917504);
  unsigned short* WkTh = (unsigned short*)(W0 + 1048576);
  unsigned short* WkTl = (unsigned short*)(W0 + 1179648);
  unsigned short* WvTh = (unsigned short*)(W0 + 1310720);
  unsigned short* WvTl = (unsigned short*)(W0 + 1441792);
  unsigned short* WaTh = (unsigned short*)(W0 + 1572864);
  unsigned short* WaTl = (unsigned short*)(W0 + 1703936);
  unsigned short* WcvTh = (unsigned short*)(W0 + 1835008);
  unsigned short* WcvTl = (unsigned short*)(W0 + 2097152);
  unsigned short* A1Th = (unsigned short*)(W0 + 2359296);
  unsigned short* A1Tl = (unsigned short*)(W0 + 2621440);
  unsigned short* A2Th = (unsigned short*)(W0 + 2883584);
  unsigned short* A2Tl = (unsigned short*)(W0 + 3014656);
  unsigned short* B1Th = (unsigned short*)(W0 + 3145728);
  unsigned short* B1Tl = (unsigned short*)(W0 + 3670016);
  unsigned short* B2Th = (unsigned short*)(W0 + 4194304);
  unsigned short* B2Tl = (unsigned short*)(W0 + 4227072);
  float* gvec = (float*)(W0 + 4259840);
  // post-loop aliases (lifetimes audited; split = same bytes as fp32):
  unsigned short* xAh  = (unsigned short*)(base);              // step 4-7
  unsigned short* xAl  = (unsigned short*)(base + 16777216);
  float* qkv           = (float*)(base + 33554432);            // step 5-6
  unsigned short* ctxh = (unsigned short*)(base + 134217728);  // step 6-7 (over asumF)
  unsigned short* ctxl = (unsigned short*)(base + 150994944);
  unsigned short* afh  = (unsigned short*)(base + 33554432);   // step 7-8 (over qkv)
  unsigned short* afl  = (unsigned short*)(base + 50331648);
  unsigned short* atfh = (unsigned short*)(base + 67108864);   // step 8-end
  unsigned short* atfl = (unsigned short*)(base + 83886080);
  unsigned short* t1h  = (unsigned short*)(base);              // step 9
  unsigned short* t1l  = (unsigned short*)(base + 33554432);
  unsigned short* t2h  = (unsigned short*)(base);              // step 10 (hi)
  unsigned short* t2l  = (unsigned short*)(base + 100663296);  // step 10 (lo)

  // 0) weight pre-convert (split bf16, [N][Kp], transposed as needed)
  convT<<<256, 256, 0, stream>>>(W_i,   nullptr, WiTh, WiTl, 111, 256, 128, 0);
  convT<<<256, 256, 0, stream>>>(W_h,   nullptr, WhTh, WhTl, 256, 256, 256, 0);
  convT<<<256, 256, 0, stream>>>(W_o,   nullptr, WoTh, WoTl, 354, 256, 384, 1);
  convT<<<256, 256, 0, stream>>>(Wq,    nullptr, WqTh, WqTl, 256, 256, 256, 0);
  convT<<<256, 256, 0, stream>>>(Wk,    nullptr, WkTh, WkTl, 256, 256, 256, 0);
  convT<<<256, 256, 0, stream>>>(Wv,    nullptr, WvTh, WvTl, 256, 256, 256, 0);
  convT<<<256, 256, 0, stream>>>(Wattn, nullptr, WaTh, WaTl, 256, 256, 256, 0);
  convT<<<256, 256, 0, stream>>>(W_vc,  W_vv,    WcvTh, WcvTl, 512, 256, 512, 2);
  convT<<<512, 256, 0, stream>>>(A1,    nullptr, A1Th, A1Tl, 256, 512, 256, 0);
  convT<<<128, 256, 0, stream>>>(A2,    nullptr, A2Th, A2Tl, 512, 128, 512, 0);
  convT<<<512, 256, 0, stream>>>(B1,    nullptr, B1Th, B1Tl, 512, 512, 512, 0);
  convT<<<32, 256, 0, stream>>>(B2,     nullptr, B2Th, B2Tl, 512, 32, 512, 0);

  // 1) h = h0 = relu(f_bonds @ W_i)  (split out)
  mgemm<0><<<dim3(1024, 2), 256, 0, stream>>>(
      f_bonds, nullptr, nullptr, WiTh, WiTl, 128, nullptr, nullptr, nullptr,
      hH, hL, N_DIR, 256, 111, 111, 256, 0, 1, 0);

  // 2) DMPNN loop
  for (int d = 0; d < 9; ++d) {
    asum_f<<<4096, 256, 0, stream>>>(hH, hL, asumF);
    msg_m<<<1024, 512, 0, stream>>>(asumF, hH, hL, WhTh, WhTl, WiTh, WiTl, f_bonds);
  }

  // 3) a_in
  asum_f<<<4096, 256, 0, stream>>>(hH, hL, asumF);
  // 4) a_feats = relu([asum | f_atoms] @ WoT + b_o)
  mgemm<2><<<dim3(256, 2), 256, 0, stream>>>(
      asumF, f_atoms, nullptr, WoTh, WoTl, 384, nullptr, nullptr, b_o,
      xAh, xAl, N_ATOMS, 256, 354, 0, 256, 0, 1, 0);
  // 5) qkv (fp32 out)
  mgemm<1><<<dim3(256, 2), 256, 0, stream>>>(
      xAh, xAl, nullptr, WqTh, WqTl, 256, nullptr, nullptr, nullptr,
      qkv, nullptr, N_ATOMS, 256, 256, 256, 768, 0, 0, 1);
  mgemm<1><<<dim3(256, 2), 256, 0, stream>>>(
      xAh, xAl, nullptr, WkTh, WkTl, 256, nullptr, nullptr, nullptr,
      qkv, nullptr, N_ATOMS, 256, 256, 256, 768, 256, 0, 1);
  mgemm<1><<<dim3(256, 2), 256, 0, stream>>>(
      xAh, xAl, nullptr, WvTh, WvTl, 256, nullptr, nullptr, nullptr,
      qkv, nullptr, N_ATOMS, 256, 256, 256, 768, 512, 0, 1);
  // 6) attention
  attn_k<<<4096, 64, 0, stream>>>(qkv, ctxh, ctxl);
  // 7) a_feats' = x + ctx @ Wattn   (addend = xA split)
  mgemm<1><<<dim3(256, 2), 256, 0, stream>>>(
      ctxh, ctxl, nullptr, WaTh, WaTl, 256, xAh, xAl, nullptr,
      afh, afl, N_ATOMS, 256, 256, 256, 256, 0, 0, 0);
  // 8) atom_feats = relu(afat @ W_vc^T + prev_hid @ W_vv^T)
  mgemm<3><<<dim3(256, 2), 256, 0, stream>>>(
      afh, afl, prev_hid, WcvTh, WcvTl, 512, nullptr, nullptr, nullptr,
      atfh, atfl, N_ATOMS, 256, 512, 256, 256, 0, 1, 0);
  // 9) atom head
  mgemm<1><<<dim3(256, 4), 256, 0, stream>>>(
      atfh, atfl, nullptr, A1Th, A1Tl, 256, nullptr, nullptr, a1,
      t1h, t1l, N_ATOMS, 512, 256, 256, 512, 0, 1, 0);
  mgemm<1><<<dim3(256, 1), 256, 0, stream>>>(
      t1h, t1l, nullptr, A2Th, A2Tl, 512, nullptr, nullptr, a2,
      out, nullptr, N_ATOMS, 128, 512, 512, 0, 0, 0, 2);
  // 10) bond head
  mgemm<4><<<dim3(512, 4), 256, 0, stream>>>(
      atfh, atfl, nullptr, B1Th, B1Tl, 512, nullptr, nullptr, b1,
      t2h, t2l, N_UND, 512, 512, 0, 512, 0, 1, 0);
  mgemm<1><<<dim3(512, 1), 256, 0, stream>>>(
      t2h, t2l, nullptr, B2Th, B2Tl, 512, nullptr, nullptr, b2b,
      out, nullptr, N_UND, 32, 512, 512, 0, 0, 0, 3);
  // 11) graph head
  gv_k<<<512, 256, 0, stream>>>(atfh, atfl, gvec);
  gh_k<<<512, 512, 0, stream>>>(gvec, G1, g1, G2, g2, out);
}